// Round 13
// baseline (236.144 us; speedup 1.0000x reference)
//
#include <hip/hip_runtime.h>
#include <hip/hip_bf16.h>

// GraphQNetwork: 2x GCNConv (9->32->64, relu) + global mean pool + station MLP.
// Round 12: co-residency attack. M processed as 16 sub-tiles (64 dst-rows x
// 128 src-cols = 16 KB); aggregation accumulates over K-halves in registers.
// LDS ~66.5 KB -> 2 blocks/CU so independent blocks fill barrier stalls
// (r11 showed intra-block occupancy doubling does nothing: 100.4 us at both).

#define NNODES 262144
#define NPG 256
#define NGRAPHS 1024
#define NEDGES 2097152
#define NFEAT 9
#define ECAP2 2560
#define T_EDGES 8192
#define NTILES (NEDGES / T_EDGES)   // 256
#define TPB 512

typedef __hip_bfloat16 bf16;
typedef short short8 __attribute__((ext_vector_type(8)));
typedef float f32x4 __attribute__((ext_vector_type(4)));

__device__ __forceinline__ float bfbits(unsigned short u) { return __uint_as_float(((unsigned)u) << 16); }
__device__ __forceinline__ unsigned short f2bbits(float v) { bf16 b = __float2bfloat16(v); return *(unsigned short*)&b; }

// ---- edge partition: 256 tiles, dense buckets (r11, unchanged) --------------

__global__ void __launch_bounds__(1024) k_gsort(const int* __restrict__ src,
                                                const int* __restrict__ dst,
                                                int* __restrict__ gcur,
                                                unsigned short* __restrict__ gout) {
    __shared__ unsigned short edg[T_EDGES];
    __shared__ unsigned short pay[T_EDGES];
    __shared__ int cnt[NGRAPHS];
    __shared__ int goff[NGRAPHS];
    int t = threadIdx.x;
    int base = blockIdx.x * T_EDGES;
    cnt[t] = 0;
    __syncthreads();
    const int4* s4 = (const int4*)(src + base);
    const int4* d4 = (const int4*)(dst + base);
#pragma unroll
    for (int k = 0; k < T_EDGES / 4096; ++k) {
        int idx = k * 1024 + t;
        int4 dv = d4[idx];
        int4 sv = s4[idx];
        int i0 = idx * 4;
        edg[i0]     = (unsigned short)(dv.x >> 8);
        edg[i0 + 1] = (unsigned short)(dv.y >> 8);
        edg[i0 + 2] = (unsigned short)(dv.z >> 8);
        edg[i0 + 3] = (unsigned short)(dv.w >> 8);
        pay[i0]     = (unsigned short)(((dv.x & 255) << 8) | (sv.x & 255));
        pay[i0 + 1] = (unsigned short)(((dv.y & 255) << 8) | (sv.y & 255));
        pay[i0 + 2] = (unsigned short)(((dv.z & 255) << 8) | (sv.z & 255));
        pay[i0 + 3] = (unsigned short)(((dv.w & 255) << 8) | (sv.w & 255));
        atomicAdd(&cnt[dv.x >> 8], 1);
        atomicAdd(&cnt[dv.y >> 8], 1);
        atomicAdd(&cnt[dv.z >> 8], 1);
        atomicAdd(&cnt[dv.w >> 8], 1);
    }
    __syncthreads();
    {
        int c = cnt[t];
        goff[t] = c ? atomicAdd(&gcur[t], c) : 0;
        cnt[t] = 0;
    }
    __syncthreads();
#pragma unroll
    for (int k = 0; k < T_EDGES / 1024; ++k) {
        int i = k * 1024 + t;
        int g = edg[i];
        int pos = atomicAdd(&cnt[g], 1);
        int off = goff[g] + pos;
        if (off < ECAP2) gout[(size_t)g * ECAP2 + off] = pay[i];
    }
}

// ---- fused per-graph kernel, 2 blocks/CU ------------------------------------

__global__ void __launch_bounds__(TPB, 4) k_fused(
    const float* __restrict__ x, const int* __restrict__ station_ids,
    const float* __restrict__ W1, const float* __restrict__ b1,
    const float* __restrict__ W2, const float* __restrict__ b2,
    const float* __restrict__ fc1W, const float* __restrict__ fc1b,
    const float* __restrict__ fc2W, const float* __restrict__ fc2b,
    const int* __restrict__ gcnt, const unsigned short* __restrict__ gedges,
    float* __restrict__ out) {

    __shared__ __align__(16) unsigned char Ms[16384];     // M sub-tile 64x128 bf16
    __shared__ __align__(16) unsigned char BufA[16896];   // EPa -> G1T [32][264] -> fc1s16
    __shared__ __align__(16) unsigned char BufB[16896];   // xsf -> H1T [32][264]
    __shared__ __align__(16) unsigned short S2q[64 * 34]; // quarter agg2' out
    __shared__ __align__(16) unsigned short W2Ts[64 * 36];// [o][k]
    __shared__ float W1s[288];
    __shared__ float dinvs[256];
    __shared__ unsigned short Rl[260];
    __shared__ unsigned char El[ECAP2];
    __shared__ unsigned int sru[512];                     // hist+cursor -> sts
    __shared__ float meanf[64];
    __shared__ float poolf[64];
    __shared__ unsigned char stmap[256];
    __shared__ float b1s[32], b2s[64], fc1bs[64], fc2ws[64];
    __shared__ int stids[8];
    __shared__ float fc2bv;

    int t = threadIdx.x;
    int g = blockIdx.x;
    int nbase = g * NPG;
    int lane = t & 63, wvid = t >> 6;                     // 8 waves
    int m = lane & 15, quad = lane >> 4;

    unsigned short* EPa = (unsigned short*)BufA;          // early
    float* xsf = (float*)BufB;                            // early
    unsigned short* G1T = (unsigned short*)BufA;          // [32][264]
    unsigned short* H1T = (unsigned short*)BufB;          // [32][264]
    unsigned short* fc1s16 = (unsigned short*)BufA;       // [128][64] late
    float* sts = (float*)sru;                             // [8][64] late

    // ---- P0: stage
    int ecnt = min(gcnt[g], ECAP2);
    {
        const uint4* gev = (const uint4*)(gedges + (size_t)g * ECAP2);
        uint4* epv = (uint4*)BufA;
        for (int i = t; i < ECAP2 / 8; i += TPB) epv[i] = gev[i];
    }
    const float* xg = x + (size_t)nbase * NFEAT;
    for (int i = t; i < NPG * NFEAT; i += TPB) xsf[i] = xg[i];
    for (int i = t; i < NFEAT * 32; i += TPB) W1s[i] = W1[i];
    for (int i = t; i < 2048; i += TPB)
        W2Ts[(i >> 5) * 36 + (i & 31)] = f2bbits(W2[(i & 31) * 64 + (i >> 5)]);
    if (t < 32) b1s[t] = b1[t];
    if (t < 64) { b2s[t] = b2[t]; fc1bs[t] = fc1b[t]; fc2ws[t] = fc2W[t]; poolf[t] = 0.f; }
    if (t < 8) stids[t] = station_ids[t];
    if (t == 0) fc2bv = fc2b[0];
    if (t < 256) { stmap[t] = 255; sru[t] = 0u; }
    __syncthreads();                                      // B1
    if (t < 8) stmap[stids[t] & 255] = (unsigned char)t;

    // ---- P0b: dst histogram
    for (int i = t; i < ecnt; i += TPB) atomicAdd(&sru[EPa[i] >> 8], 1u);
    __syncthreads();                                      // B2

    // ---- P0c: single-wave scan -> Rl, cursors, dinvs
    if (wvid == 0) {
        int b0 = sru[lane * 4], b1v = sru[lane * 4 + 1], b2v = sru[lane * 4 + 2], b3 = sru[lane * 4 + 3];
        int s = b0 + b1v + b2v + b3;
        int inc = s;
        for (int off = 1; off < 64; off <<= 1) {
            int y = __shfl_up(inc, off);
            if (lane >= off) inc += y;
        }
        int run = inc - s;
        Rl[lane * 4] = (unsigned short)run; sru[256 + lane * 4] = run;
        dinvs[lane * 4] = rsqrtf((float)(b0 + 1)); run += b0;
        Rl[lane * 4 + 1] = (unsigned short)run; sru[257 + lane * 4] = run;
        dinvs[lane * 4 + 1] = rsqrtf((float)(b1v + 1)); run += b1v;
        Rl[lane * 4 + 2] = (unsigned short)run; sru[258 + lane * 4] = run;
        dinvs[lane * 4 + 2] = rsqrtf((float)(b2v + 1)); run += b2v;
        Rl[lane * 4 + 3] = (unsigned short)run; sru[259 + lane * 4] = run;
        dinvs[lane * 4 + 3] = rsqrtf((float)(b3 + 1));
        if (lane == 63) Rl[256] = (unsigned short)inc;
    }
    __syncthreads();                                      // B3

    // ---- P0d: scatter -> El
    for (int i = t; i < ecnt; i += TPB) {
        unsigned short v = EPa[i];
        unsigned p = atomicAdd(&sru[256 + (v >> 8)], 1u);
        if (p < ECAP2) El[p] = (unsigned char)(v & 255);
    }
    __syncthreads();                                      // B4

    // ---- P0e: lin1 -> G1T (overwrites EPa; reads xsf)
    {
        int n = t >> 1, hf = t & 1;
        float xv[NFEAT];
#pragma unroll
        for (int k = 0; k < NFEAT; k++) xv[k] = xsf[n * NFEAT + k];
#pragma unroll 4
        for (int ci = 0; ci < 16; ci++) {
            int c = hf * 16 + ci;
            float acc = 0.f;
#pragma unroll
            for (int k = 0; k < NFEAT; k++) acc += xv[k] * W1s[k * 32 + c];
            G1T[c * 264 + n] = f2bbits(acc);
        }
    }
    __syncthreads();                                      // B5

    // M sub-tile build: 64 rows (qt) x 128 cols (kh). 8 thr/row; each thread
    // owns s-sixteenth q -> exactly 2 swizzle chunks (self-zeroed, no barrier).
#define BUILD_M(QT, KH)                                                         \
    {                                                                           \
        int dl = t >> 3, q = t & 7;                                             \
        int d = (QT) * 64 + dl;                                                 \
        int c0 = (2 * q) ^ (dl & 15), c1 = (2 * q + 1) ^ (dl & 15);             \
        uint4 z = {0u, 0u, 0u, 0u};                                             \
        *(uint4*)(Ms + dl * 256 + c0 * 16) = z;                                 \
        *(uint4*)(Ms + dl * 256 + c1 * 16) = z;                                 \
        float did = dinvs[d];                                                   \
        if ((d >> 7) == (KH) && ((d >> 4) & 7) == q) {                          \
            int sp = d & 127;                                                   \
            *(unsigned short*)(Ms + dl * 256 + (((sp >> 3) ^ (dl & 15)) * 16) + (sp & 7) * 2) \
                = f2bbits(did * did);                                           \
        }                                                                       \
        int r0 = Rl[d], r1 = Rl[d + 1];                                         \
        for (int e = r0; e < r1; ++e) {                                         \
            int s = El[e];                                                      \
            if ((s >> 7) == (KH) && ((s >> 4) & 7) == q) {                      \
                int sp = s & 127;                                               \
                unsigned short* p =                                             \
                    (unsigned short*)(Ms + dl * 256 + (((sp >> 3) ^ (dl & 15)) * 16) + (sp & 7) * 2); \
                *p = f2bbits(bfbits(*p) + did * dinvs[s]);                      \
            }                                                                   \
        }                                                                       \
    }

    int mt = wvid >> 1, nt = wvid & 1;

    // ---- Pass 1: h1 = relu(M @ G1 + b1), per quarter, K-halves in registers
    for (int qt = 0; qt < 4; ++qt) {
        f32x4 acc = {};
        for (int kh = 0; kh < 2; ++kh) {
            BUILD_M(qt, kh)
            __syncthreads();
            for (int kt = 0; kt < 4; ++kt) {
                short8 af = *(const short8*)(Ms + (mt * 16 + m) * 256 + (((kt * 4 + quad) ^ m) * 16));
                short8 bf = *(const short8*)(BufA + (size_t)(nt * 16 + m) * 528 + kh * 256 + kt * 64 + quad * 16);
                acc = __builtin_amdgcn_mfma_f32_16x16x32_bf16(af, bf, acc, 0, 0, 0);
            }
            if (kh == 0) __syncthreads();
        }
        {
            int ch = nt * 16 + m;
            float bb = b1s[ch];
#pragma unroll
            for (int r = 0; r < 4; ++r) {
                int node = qt * 64 + mt * 16 + quad * 4 + r;
                H1T[ch * 264 + node] = f2bbits(fmaxf(acc[r] + bb, 0.f));
            }
        }
        __syncthreads();
    }

    // ---- Pass 2: S2 = M @ H1 (quarter) -> lin2 -> pool/stations
    for (int qt = 0; qt < 4; ++qt) {
        f32x4 acc = {};
        for (int kh = 0; kh < 2; ++kh) {
            BUILD_M(qt, kh)
            if (qt == 0 && kh == 0)                       // G1T dead: stage fc1 bf16
                for (int i = t; i < 8192; i += TPB) fc1s16[i] = f2bbits(fc1W[i]);
            __syncthreads();
            for (int kt = 0; kt < 4; ++kt) {
                short8 af = *(const short8*)(Ms + (mt * 16 + m) * 256 + (((kt * 4 + quad) ^ m) * 16));
                short8 bf = *(const short8*)(BufB + (size_t)(nt * 16 + m) * 528 + kh * 256 + kt * 64 + quad * 16);
                acc = __builtin_amdgcn_mfma_f32_16x16x32_bf16(af, bf, acc, 0, 0, 0);
            }
            if (kh == 0) __syncthreads();
        }
        {
            int ch = nt * 16 + m;
#pragma unroll
            for (int r = 0; r < 4; ++r)
                S2q[(mt * 16 + quad * 4 + r) * 34 + ch] = f2bbits(acc[r]);
        }
        __syncthreads();
        // lin2 on this quarter: 16 tiles (4 node-tiles x 4 out-tiles), 2/wave
#pragma unroll
        for (int j = 0; j < 2; ++j) {
            int tau = wvid * 2 + j;
            int mt2 = tau >> 2, ot = tau & 3;
            short8 af = *(const short8*)((const unsigned char*)S2q + (size_t)(mt2 * 16 + m) * 68 + quad * 16);
            short8 bf = *(const short8*)((const unsigned char*)W2Ts + (size_t)(ot * 16 + m) * 72 + quad * 16);
            f32x4 c = {};
            c = __builtin_amdgcn_mfma_f32_16x16x32_bf16(af, bf, c, 0, 0, 0);
            int ch = ot * 16 + m;
            float bb = b2s[ch];
            float hv[4];
            float p = 0.f;
#pragma unroll
            for (int r = 0; r < 4; ++r) { hv[r] = fmaxf(c[r] + bb, 0.f); p += hv[r]; }
            p += __shfl_down(p, 32);
            p += __shfl_down(p, 16);
            if (quad == 0) atomicAdd(&poolf[ch], p);
#pragma unroll
            for (int r = 0; r < 4; ++r) {
                int node = qt * 64 + mt2 * 16 + quad * 4 + r;
                int si = stmap[node];
                if (si != 255) sts[si * 64 + ch] = hv[r];
            }
        }
        __syncthreads();
    }

    // ---- mean
    if (t < 64) meanf[t] = poolf[t] * (1.0f / 256.0f);
    __syncthreads();

    // ---- MLP, one wave per station
    {
        int l = lane;
        int si = wvid;
        const float* st = sts + si * 64;
        float acc = 0.f;
#pragma unroll 8
        for (int k = 0; k < 64; k++) acc += st[k] * bfbits(fc1s16[k * 64 + l]);
#pragma unroll 8
        for (int k = 0; k < 64; k++) acc += meanf[k] * bfbits(fc1s16[(64 + k) * 64 + l]);
        float a = fmaxf(acc + fc1bs[l], 0.f) * fc2ws[l];
        for (int off = 32; off > 0; off >>= 1) a += __shfl_down(a, off);
        if (l == 0) out[g * 8 + si] = a + fc2bv;
    }
#undef BUILD_M
}

// ---- launch -----------------------------------------------------------------

extern "C" void kernel_launch(void* const* d_in, const int* in_sizes, int n_in,
                              void* d_out, int out_size, void* d_ws, size_t ws_size,
                              hipStream_t stream) {
    const float* x = (const float*)d_in[0];
    const int* ei = (const int*)d_in[1];
    const int* station_ids = (const int*)d_in[2];
    const float* W1 = (const float*)d_in[3];
    const float* b1 = (const float*)d_in[4];
    const float* W2 = (const float*)d_in[5];
    const float* bias2 = (const float*)d_in[6];
    const float* fc1W = (const float*)d_in[7];
    const float* fc1b = (const float*)d_in[8];
    const float* fc2W = (const float*)d_in[9];
    const float* fc2b = (const float*)d_in[10];
    float* out = (float*)d_out;
    (void)in_sizes; (void)n_in; (void)out_size; (void)ws_size;

    char* ws = (char*)d_ws;
    int* gcur = (int*)ws;                                     // 4 KiB
    unsigned short* gout = (unsigned short*)(ws + 0x2000);    // 5.24 MB

    const int* esrc = ei;
    const int* edst = ei + NEDGES;

    hipMemsetAsync(gcur, 0, NGRAPHS * sizeof(int), stream);
    k_gsort<<<NTILES, 1024, 0, stream>>>(esrc, edst, gcur, gout);
    k_fused<<<NGRAPHS, TPB, 0, stream>>>(x, station_ids, W1, b1, W2, bias2,
                                         fc1W, fc1b, fc2W, fc2b, gcur, gout, out);
}

// Round 14
// 199.475 us; speedup vs baseline: 1.1838x; 1.1838x over previous
//
#include <hip/hip_runtime.h>
#include <hip/hip_bf16.h>

// GraphQNetwork: 2x GCNConv (9->32->64, relu) + global mean pool + station MLP.
// Round 13: persistent fused blocks — 256 blocks x 4 graphs, r10 body (the
// 100us known-best), weights staged ONCE per block (was 4x). gsort: gcur
// strided 64B/counter to stop cross-XCD atomic line ping-pong.

#define NNODES 262144
#define NPG 256
#define NGRAPHS 1024
#define NEDGES 2097152
#define NFEAT 9
#define ECAP2 2560
#define T_EDGES 8192
#define NTILES (NEDGES / T_EDGES)   // 256
#define TPB 512
#define NBLK 256

typedef __hip_bfloat16 bf16;
typedef short short8 __attribute__((ext_vector_type(8)));
typedef float f32x4 __attribute__((ext_vector_type(4)));

__device__ __forceinline__ float bfbits(unsigned short u) { return __uint_as_float(((unsigned)u) << 16); }
__device__ __forceinline__ unsigned short f2bbits(float v) { bf16 b = __float2bfloat16(v); return *(unsigned short*)&b; }

// ---- edge partition: 256 tiles, dense buckets (r11 + strided cursors) -------

__global__ void __launch_bounds__(1024) k_gsort(const int* __restrict__ src,
                                                const int* __restrict__ dst,
                                                int* __restrict__ gcur,
                                                unsigned short* __restrict__ gout) {
    __shared__ unsigned short edg[T_EDGES];
    __shared__ unsigned short pay[T_EDGES];
    __shared__ int cnt[NGRAPHS];
    __shared__ int goff[NGRAPHS];
    int t = threadIdx.x;
    int base = blockIdx.x * T_EDGES;
    cnt[t] = 0;
    __syncthreads();
    const int4* s4 = (const int4*)(src + base);
    const int4* d4 = (const int4*)(dst + base);
#pragma unroll
    for (int k = 0; k < T_EDGES / 4096; ++k) {
        int idx = k * 1024 + t;
        int4 dv = d4[idx];
        int4 sv = s4[idx];
        int i0 = idx * 4;
        edg[i0]     = (unsigned short)(dv.x >> 8);
        edg[i0 + 1] = (unsigned short)(dv.y >> 8);
        edg[i0 + 2] = (unsigned short)(dv.z >> 8);
        edg[i0 + 3] = (unsigned short)(dv.w >> 8);
        pay[i0]     = (unsigned short)(((dv.x & 255) << 8) | (sv.x & 255));
        pay[i0 + 1] = (unsigned short)(((dv.y & 255) << 8) | (sv.y & 255));
        pay[i0 + 2] = (unsigned short)(((dv.z & 255) << 8) | (sv.z & 255));
        pay[i0 + 3] = (unsigned short)(((dv.w & 255) << 8) | (sv.w & 255));
        atomicAdd(&cnt[dv.x >> 8], 1);
        atomicAdd(&cnt[dv.y >> 8], 1);
        atomicAdd(&cnt[dv.z >> 8], 1);
        atomicAdd(&cnt[dv.w >> 8], 1);
    }
    __syncthreads();
    {
        int c = cnt[t];
        goff[t] = c ? atomicAdd(&gcur[t * 16], c) : 0;   // one counter per 64B line
        cnt[t] = 0;
    }
    __syncthreads();
#pragma unroll
    for (int k = 0; k < T_EDGES / 1024; ++k) {
        int i = k * 1024 + t;
        int g = edg[i];
        int pos = atomicAdd(&cnt[g], 1);
        int off = goff[g] + pos;
        if (off < ECAP2) gout[(size_t)g * ECAP2 + off] = pay[i];
    }
}

// ---- persistent fused kernel: 256 blocks x 4 graphs -------------------------

__global__ void __launch_bounds__(TPB) k_fused(
    const float* __restrict__ x, const int* __restrict__ station_ids,
    const float* __restrict__ W1, const float* __restrict__ b1,
    const float* __restrict__ W2, const float* __restrict__ b2,
    const float* __restrict__ fc1W, const float* __restrict__ fc1b,
    const float* __restrict__ fc2W, const float* __restrict__ fc2b,
    const int* __restrict__ gcnt, const unsigned short* __restrict__ gedges,
    float* __restrict__ out) {

    __shared__ __align__(16) unsigned char Ms[65536];     // half-M: 128 x 512 B
    __shared__ __align__(16) unsigned char BufA[17024];   // G1T [32][266]
    __shared__ __align__(16) unsigned char BufB[17024];   // H1T [32][266]
    __shared__ __align__(16) unsigned char BufC[19456];   // xsf(9216)+EPa(5120) -> S2 [256][38]
    __shared__ __align__(16) unsigned short fc1s16[8192]; // bf16 [128][64] (persistent)
    __shared__ __align__(16) unsigned short W2Ts[64 * 40];
    __shared__ float W1s[288];
    __shared__ float dinvs[256];
    __shared__ unsigned short Rl[260];
    __shared__ unsigned char El[ECAP2];
    __shared__ unsigned int sru[512];
    __shared__ float sts[512];
    __shared__ float meanf[64];
    __shared__ float poolf[64];
    __shared__ unsigned char stmap[256];
    __shared__ float b1s[32], b2s[64], fc1bs[64], fc2ws[64];
    __shared__ int stids[8];
    __shared__ float fc2bv;

    int t = threadIdx.x;
    int lane = t & 63, wvid = t >> 6;                     // 8 waves
    int m = lane & 15, quad = lane >> 4;

    float* xsf = (float*)BufC;
    unsigned short* EPa = (unsigned short*)(BufC + 9216);
    unsigned short* G1T = (unsigned short*)BufA;
    unsigned short* H1T = (unsigned short*)BufB;
    unsigned short* S2 = (unsigned short*)BufC;

    // ---- persistent staging (once per block) ----
    for (int i = t; i < NFEAT * 32; i += TPB) W1s[i] = W1[i];
    for (int i = t; i < 2048; i += TPB)
        W2Ts[(i >> 5) * 40 + (i & 31)] = f2bbits(W2[(i & 31) * 64 + (i >> 5)]);
    for (int i = t; i < 8192; i += TPB) fc1s16[i] = f2bbits(fc1W[i]);
    if (t < 32) b1s[t] = b1[t];
    if (t < 64) { b2s[t] = b2[t]; fc1bs[t] = fc1b[t]; fc2ws[t] = fc2W[t]; }
    if (t < 8) stids[t] = station_ids[t];
    if (t == 0) fc2bv = fc2b[0];
    if (t < 256) stmap[t] = 255;
    __syncthreads();
    if (t < 8) stmap[stids[t] & 255] = (unsigned char)t;

    for (int g = blockIdx.x; g < NGRAPHS; g += NBLK) {
        int nbase = g * NPG;

        // ---- P0: per-graph staging + zero Ms
        int ecnt = min(gcnt[g * 16], ECAP2);
        {
            const uint4* gev = (const uint4*)(gedges + (size_t)g * ECAP2);
            uint4* epv = (uint4*)EPa;
            for (int i = t; i < ECAP2 / 8; i += TPB) epv[i] = gev[i];
        }
        const float* xg = x + (size_t)nbase * NFEAT;
        for (int i = t; i < NPG * NFEAT; i += TPB) xsf[i] = xg[i];
        if (t < 64) poolf[t] = 0.f;
        if (t < 256) sru[t] = 0u;
        {
            uint4* mz = (uint4*)Ms;
            uint4 z = {0u, 0u, 0u, 0u};
            for (int i = t; i < 4096; i += TPB) mz[i] = z;
        }
        __syncthreads();                                  // B1

        // ---- P0b: dst histogram
        for (int i = t; i < ecnt; i += TPB) atomicAdd(&sru[EPa[i] >> 8], 1u);
        __syncthreads();                                  // B2

        // ---- P0c: single-wave scan -> Rl, cursors, dinvs
        if (wvid == 0) {
            int b0 = sru[lane * 4], b1v = sru[lane * 4 + 1], b2v = sru[lane * 4 + 2], b3 = sru[lane * 4 + 3];
            int s = b0 + b1v + b2v + b3;
            int inc = s;
            for (int off = 1; off < 64; off <<= 1) {
                int y = __shfl_up(inc, off);
                if (lane >= off) inc += y;
            }
            int run = inc - s;
            Rl[lane * 4] = (unsigned short)run; sru[256 + lane * 4] = run;
            dinvs[lane * 4] = rsqrtf((float)(b0 + 1)); run += b0;
            Rl[lane * 4 + 1] = (unsigned short)run; sru[257 + lane * 4] = run;
            dinvs[lane * 4 + 1] = rsqrtf((float)(b1v + 1)); run += b1v;
            Rl[lane * 4 + 2] = (unsigned short)run; sru[258 + lane * 4] = run;
            dinvs[lane * 4 + 2] = rsqrtf((float)(b2v + 1)); run += b2v;
            Rl[lane * 4 + 3] = (unsigned short)run; sru[259 + lane * 4] = run;
            dinvs[lane * 4 + 3] = rsqrtf((float)(b3 + 1));
            if (lane == 63) Rl[256] = (unsigned short)inc;
        }
        __syncthreads();                                  // B3

        // ---- P0d: scatter -> El
        for (int i = t; i < ecnt; i += TPB) {
            unsigned short v = EPa[i];
            unsigned p = atomicAdd(&sru[256 + (v >> 8)], 1u);
            if (p < ECAP2) El[p] = (unsigned char)(v & 255);
        }
        __syncthreads();                                  // B4

        // ---- P1: t<256 builds M(h0) (2 thr/row); t>=256 lin1 -> G1T
        if (t < 256) {
            int dl = t >> 1, q = t & 1;
            int d = dl;
            float did = dinvs[d];
            if ((d >> 7) == q)
                *(unsigned short*)(Ms + dl * 512 + (((d >> 3) ^ (d & 15)) * 16) + (d & 7) * 2)
                    = f2bbits(did * did);
            int r0 = Rl[d], r1 = Rl[d + 1];
            for (int e = r0; e < r1; ++e) {
                int s = El[e];
                if ((s >> 7) == q) {
                    unsigned short* p =
                        (unsigned short*)(Ms + dl * 512 + (((s >> 3) ^ (d & 15)) * 16) + (s & 7) * 2);
                    *p = f2bbits(bfbits(*p) + did * dinvs[s]);
                }
            }
        } else {
            int n = t - 256;
            float xv[NFEAT];
#pragma unroll
            for (int k = 0; k < NFEAT; k++) xv[k] = xsf[n * NFEAT + k];
#pragma unroll 4
            for (int c = 0; c < 32; c++) {
                float acc = 0.f;
#pragma unroll
                for (int k = 0; k < NFEAT; k++) acc += xv[k] * W1s[k * 32 + c];
                G1T[c * 266 + n] = f2bbits(acc);
            }
        }
        __syncthreads();                                  // B5

        // ---- P2: agg1(h0) -> H1T nodes 0..127
        {
            f32x4 acc[2] = {};
            for (int kt = 0; kt < 8; ++kt) {
                short8 af = *(const short8*)(Ms + (wvid * 16 + m) * 512 + (((kt * 4 + quad) ^ m) * 16));
                short8 bf0 = *(const short8*)(BufA + (size_t)m * 532 + kt * 64 + quad * 16);
                short8 bf1 = *(const short8*)(BufA + (size_t)(16 + m) * 532 + kt * 64 + quad * 16);
                acc[0] = __builtin_amdgcn_mfma_f32_16x16x32_bf16(af, bf0, acc[0], 0, 0, 0);
                acc[1] = __builtin_amdgcn_mfma_f32_16x16x32_bf16(af, bf1, acc[1], 0, 0, 0);
            }
#pragma unroll
            for (int ni = 0; ni < 2; ++ni) {
                int ch = ni * 16 + m;
                float bb = b1s[ch];
#pragma unroll
                for (int r = 0; r < 4; ++r) {
                    int node = wvid * 16 + quad * 4 + r;
                    H1T[ch * 266 + node] = f2bbits(fmaxf(acc[ni][r] + bb, 0.f));
                }
            }
        }
        __syncthreads();                                  // B6

        // ---- P3: zero Ms; build M(h1) (4 thr/row)
        {
            uint4* mz = (uint4*)Ms;
            uint4 z = {0u, 0u, 0u, 0u};
            for (int i = t; i < 4096; i += TPB) mz[i] = z;
        }
        __syncthreads();                                  // B7
        {
            int dl = t >> 2, q = t & 3;
            int d = 128 + dl;
            float did = dinvs[d];
            if (((d & 255) >> 6) == q) {
                int sd = d & 255;
                *(unsigned short*)(Ms + dl * 512 + (((sd >> 3) ^ (d & 15)) * 16) + (sd & 7) * 2)
                    = f2bbits(did * did);
            }
            int r0 = Rl[d], r1 = Rl[d + 1];
            for (int e = r0; e < r1; ++e) {
                int s = El[e];
                if ((s >> 6) == q) {
                    unsigned short* p =
                        (unsigned short*)(Ms + dl * 512 + (((s >> 3) ^ (d & 15)) * 16) + (s & 7) * 2);
                    *p = f2bbits(bfbits(*p) + did * dinvs[s]);
                }
            }
        }
        __syncthreads();                                  // B8

        // ---- P4: agg1(h1) -> H1T nodes 128..255
        {
            f32x4 acc[2] = {};
            for (int kt = 0; kt < 8; ++kt) {
                short8 af = *(const short8*)(Ms + (wvid * 16 + m) * 512 + (((kt * 4 + quad) ^ m) * 16));
                short8 bf0 = *(const short8*)(BufA + (size_t)m * 532 + kt * 64 + quad * 16);
                short8 bf1 = *(const short8*)(BufA + (size_t)(16 + m) * 532 + kt * 64 + quad * 16);
                acc[0] = __builtin_amdgcn_mfma_f32_16x16x32_bf16(af, bf0, acc[0], 0, 0, 0);
                acc[1] = __builtin_amdgcn_mfma_f32_16x16x32_bf16(af, bf1, acc[1], 0, 0, 0);
            }
#pragma unroll
            for (int ni = 0; ni < 2; ++ni) {
                int ch = ni * 16 + m;
                float bb = b1s[ch];
#pragma unroll
                for (int r = 0; r < 4; ++r) {
                    int node = 128 + wvid * 16 + quad * 4 + r;
                    H1T[ch * 266 + node] = f2bbits(fmaxf(acc[ni][r] + bb, 0.f));
                }
            }
        }
        __syncthreads();                                  // B9

        // ---- P5: agg2'(h1) [M(h1) resident] -> S2 rows 128..255
        {
            f32x4 acc[2] = {};
            for (int kt = 0; kt < 8; ++kt) {
                short8 af = *(const short8*)(Ms + (wvid * 16 + m) * 512 + (((kt * 4 + quad) ^ m) * 16));
                short8 bf0 = *(const short8*)(BufB + (size_t)m * 532 + kt * 64 + quad * 16);
                short8 bf1 = *(const short8*)(BufB + (size_t)(16 + m) * 532 + kt * 64 + quad * 16);
                acc[0] = __builtin_amdgcn_mfma_f32_16x16x32_bf16(af, bf0, acc[0], 0, 0, 0);
                acc[1] = __builtin_amdgcn_mfma_f32_16x16x32_bf16(af, bf1, acc[1], 0, 0, 0);
            }
#pragma unroll
            for (int ni = 0; ni < 2; ++ni) {
                int ch = ni * 16 + m;
#pragma unroll
                for (int r = 0; r < 4; ++r) {
                    int node = 128 + wvid * 16 + quad * 4 + r;
                    S2[node * 38 + ch] = f2bbits(acc[ni][r]);
                }
            }
        }
        __syncthreads();                                  // B10

        // ---- P6: zero Ms; rebuild M(h0) (4 thr/row)
        {
            uint4* mz = (uint4*)Ms;
            uint4 z = {0u, 0u, 0u, 0u};
            for (int i = t; i < 4096; i += TPB) mz[i] = z;
        }
        __syncthreads();                                  // B11
        {
            int dl = t >> 2, q = t & 3;
            int d = dl;
            float did = dinvs[d];
            if ((d >> 6) == q)
                *(unsigned short*)(Ms + dl * 512 + (((d >> 3) ^ (d & 15)) * 16) + (d & 7) * 2)
                    = f2bbits(did * did);
            int r0 = Rl[d], r1 = Rl[d + 1];
            for (int e = r0; e < r1; ++e) {
                int s = El[e];
                if ((s >> 6) == q) {
                    unsigned short* p =
                        (unsigned short*)(Ms + dl * 512 + (((s >> 3) ^ (d & 15)) * 16) + (s & 7) * 2);
                    *p = f2bbits(bfbits(*p) + did * dinvs[s]);
                }
            }
        }
        __syncthreads();                                  // B12

        // ---- P7: agg2'(h0) -> S2 rows 0..127
        {
            f32x4 acc[2] = {};
            for (int kt = 0; kt < 8; ++kt) {
                short8 af = *(const short8*)(Ms + (wvid * 16 + m) * 512 + (((kt * 4 + quad) ^ m) * 16));
                short8 bf0 = *(const short8*)(BufB + (size_t)m * 532 + kt * 64 + quad * 16);
                short8 bf1 = *(const short8*)(BufB + (size_t)(16 + m) * 532 + kt * 64 + quad * 16);
                acc[0] = __builtin_amdgcn_mfma_f32_16x16x32_bf16(af, bf0, acc[0], 0, 0, 0);
                acc[1] = __builtin_amdgcn_mfma_f32_16x16x32_bf16(af, bf1, acc[1], 0, 0, 0);
            }
#pragma unroll
            for (int ni = 0; ni < 2; ++ni) {
                int ch = ni * 16 + m;
#pragma unroll
                for (int r = 0; r < 4; ++r) {
                    int node = wvid * 16 + quad * 4 + r;
                    S2[node * 38 + ch] = f2bbits(acc[ni][r]);
                }
            }
        }
        __syncthreads();                                  // B13

        // ---- P8: lin2 = relu(S2@W2+b2); pool + stations from accumulators
        {
#pragma unroll
            for (int mi = 0; mi < 2; ++mi) {
                int mt = wvid * 2 + mi;
                short8 af = *(const short8*)(BufC + (size_t)(mt * 16 + m) * 76 + quad * 16);
#pragma unroll
                for (int ni = 0; ni < 4; ++ni) {
                    short8 bf = *(const short8*)((const unsigned char*)W2Ts + (size_t)(ni * 16 + m) * 80 + quad * 16);
                    f32x4 c = {};
                    c = __builtin_amdgcn_mfma_f32_16x16x32_bf16(af, bf, c, 0, 0, 0);
                    int ch = ni * 16 + m;
                    float bb = b2s[ch];
                    float hv[4];
                    float p = 0.f;
#pragma unroll
                    for (int r = 0; r < 4; ++r) { hv[r] = fmaxf(c[r] + bb, 0.f); p += hv[r]; }
                    p += __shfl_down(p, 32);
                    p += __shfl_down(p, 16);
                    if (quad == 0) atomicAdd(&poolf[ch], p);
#pragma unroll
                    for (int r = 0; r < 4; ++r) {
                        int node = mt * 16 + quad * 4 + r;
                        int si = stmap[node];
                        if (si != 255) sts[si * 64 + ch] = hv[r];
                    }
                }
            }
        }
        __syncthreads();                                  // B14

        // ---- P9: mean
        if (t < 64) meanf[t] = poolf[t] * (1.0f / 256.0f);
        __syncthreads();                                  // B15

        // ---- P10: MLP, one wave per station
        {
            int l = lane;
            int si = wvid;
            const float* st = sts + si * 64;
            float acc = 0.f;
#pragma unroll 8
            for (int k = 0; k < 64; k++) acc += st[k] * bfbits(fc1s16[k * 64 + l]);
#pragma unroll 8
            for (int k = 0; k < 64; k++) acc += meanf[k] * bfbits(fc1s16[(64 + k) * 64 + l]);
            float a = fmaxf(acc + fc1bs[l], 0.f) * fc2ws[l];
            for (int off = 32; off > 0; off >>= 1) a += __shfl_down(a, off);
            if (l == 0) out[g * 8 + si] = a + fc2bv;
        }
        __syncthreads();                                  // B16 (loop hazard fence)
    }
}

// ---- launch -----------------------------------------------------------------

extern "C" void kernel_launch(void* const* d_in, const int* in_sizes, int n_in,
                              void* d_out, int out_size, void* d_ws, size_t ws_size,
                              hipStream_t stream) {
    const float* x = (const float*)d_in[0];
    const int* ei = (const int*)d_in[1];
    const int* station_ids = (const int*)d_in[2];
    const float* W1 = (const float*)d_in[3];
    const float* b1 = (const float*)d_in[4];
    const float* W2 = (const float*)d_in[5];
    const float* bias2 = (const float*)d_in[6];
    const float* fc1W = (const float*)d_in[7];
    const float* fc1b = (const float*)d_in[8];
    const float* fc2W = (const float*)d_in[9];
    const float* fc2b = (const float*)d_in[10];
    float* out = (float*)d_out;
    (void)in_sizes; (void)n_in; (void)out_size; (void)ws_size;

    char* ws = (char*)d_ws;
    int* gcur = (int*)ws;                                     // 64 KiB, stride-16 counters
    unsigned short* gout = (unsigned short*)(ws + 0x10000);   // 5.24 MB

    const int* esrc = ei;
    const int* edst = ei + NEDGES;

    hipMemsetAsync(gcur, 0, NGRAPHS * 16 * sizeof(int), stream);
    k_gsort<<<NTILES, 1024, 0, stream>>>(esrc, edst, gcur, gout);
    k_fused<<<NBLK, TPB, 0, stream>>>(x, station_ids, W1, b1, W2, bias2,
                                      fc1W, fc1b, fc2W, fc2b, gcur, gout, out);
}